// Round 9
// baseline (1724.224 us; speedup 1.0000x reference)
//
#include <hip/hip_runtime.h>

#define N_TOTAL 60000
#define N_X     50000
#define N_EDGE  1920000
#define NFEAT   512
#define NHID    256
#define SLOTS   96      // fixed per-row edge capacity; Poisson(32) max over 60000 rows ~ 60
#define NCHUNK  8       // feature chunks of 32 feats (64 B bf16); chunk c == XCD c (HW_REG_XCC_ID)

typedef __attribute__((ext_vector_type(8))) short bf16x8;
typedef __attribute__((ext_vector_type(4))) float f32x4;
typedef __attribute__((ext_vector_type(4))) unsigned u32x4;

__device__ __forceinline__ unsigned short f2bf(float f) {
    unsigned u = __float_as_uint(f);
    unsigned r = (u + 0x7FFFu + ((u >> 16) & 1u)) >> 16;   // RNE
    return (unsigned short)r;
}
__device__ __forceinline__ float bf_lo(unsigned u) { return __uint_as_float(u << 16); }
__device__ __forceinline__ float bf_hi(unsigned u) { return __uint_as_float(u & 0xFFFF0000u); }

// ---------------- all W[K][256] fp32 -> WT[256][K] bf16 in one kernel ----------------
__global__ __launch_bounds__(256)
void cvt_w_all_kernel(const float* __restrict__ w1, const float* __restrict__ w2,
                      const float* __restrict__ w3, short* __restrict__ w1T,
                      short* __restrict__ w2T, short* __restrict__ w3T)
{
    int n = blockIdx.x;
    for (int k = threadIdx.x; k < NFEAT; k += 256)
        w1T[(size_t)n * NFEAT + k] = (short)f2bf(w1[(size_t)k * NHID + n]);
    for (int k = threadIdx.x; k < NHID; k += 256)
        w2T[(size_t)n * NHID + k] = (short)f2bf(w2[(size_t)k * NHID + n]);
    for (int k = threadIdx.x; k < NHID; k += 256)
        w3T[(size_t)n * NHID + k] = (short)f2bf(w3[(size_t)k * NHID + n]);
}

// ---------------- bf16 MFMA GEMM: C = A[M x K] @ BT[256 x K]^T ----------------
// C is written in feature-chunked layout: C[(col>>5)][row][col&31], chunk stride M*32.
#define LDA 40   // padded LDS row stride (shorts): 80B -> 2-way bank alias only (free)

template<bool AF32>
__global__ __launch_bounds__(256)
void gemm_bt_kernel(const float* __restrict__ Af, const float* __restrict__ A2f, int split,
                    const short* __restrict__ Ab, const short* __restrict__ BT,
                    short* __restrict__ C, int M, int K)
{
    __shared__ short As[128 * LDA];
    __shared__ short Bs[128 * LDA];
    const int t    = threadIdx.x;
    const int lane = t & 63;
    const int wave = t >> 6;
    const int wm   = wave & 1;
    const int wn   = wave >> 1;
    const int l16  = lane & 15;
    const int quad = lane >> 4;
    const int bm   = blockIdx.x * 128;
    const int bn   = blockIdx.y * 128;

    f32x4 acc[4][4] = {};

    const int srow = t >> 2;
    const int sch  = t & 3;
    const int frow = t >> 1;
    const int fh   = t & 1;

    for (int kk = 0; kk < K; kk += 32) {
        if (AF32) {
            int row = bm + frow;
            float4 v0 = {}, v1 = {}, v2 = {}, v3 = {};
            if (row < M) {
                const float* src = (row < split) ? (Af + (size_t)row * K)
                                                 : (A2f + (size_t)(row - split) * K);
                const float4* p = (const float4*)(src + kk + fh * 16);
                v0 = p[0]; v1 = p[1]; v2 = p[2]; v3 = p[3];
            }
            short* dst = &As[frow * LDA + fh * 16];
            short tmp[16] = {
                (short)f2bf(v0.x), (short)f2bf(v0.y), (short)f2bf(v0.z), (short)f2bf(v0.w),
                (short)f2bf(v1.x), (short)f2bf(v1.y), (short)f2bf(v1.z), (short)f2bf(v1.w),
                (short)f2bf(v2.x), (short)f2bf(v2.y), (short)f2bf(v2.z), (short)f2bf(v2.w),
                (short)f2bf(v3.x), (short)f2bf(v3.y), (short)f2bf(v3.z), (short)f2bf(v3.w)};
            *(bf16x8*)(dst)     = *(const bf16x8*)&tmp[0];
            *(bf16x8*)(dst + 8) = *(const bf16x8*)&tmp[8];
        } else {
            bf16x8 va0 = {}, va1 = {};
            int r0 = bm + srow, r1 = bm + srow + 64;
            if (r0 < M) va0 = *(const bf16x8*)(Ab + (size_t)r0 * K + kk + sch * 8);
            if (r1 < M) va1 = *(const bf16x8*)(Ab + (size_t)r1 * K + kk + sch * 8);
            *(bf16x8*)&As[srow * LDA + sch * 8]        = va0;
            *(bf16x8*)&As[(srow + 64) * LDA + sch * 8] = va1;
        }
        {
            bf16x8 vb0 = *(const bf16x8*)(BT + (size_t)(bn + srow) * K + kk + sch * 8);
            bf16x8 vb1 = *(const bf16x8*)(BT + (size_t)(bn + srow + 64) * K + kk + sch * 8);
            *(bf16x8*)&Bs[srow * LDA + sch * 8]        = vb0;
            *(bf16x8*)&Bs[(srow + 64) * LDA + sch * 8] = vb1;
        }
        __syncthreads();

        bf16x8 af[4], bfr[4];
        #pragma unroll
        for (int i = 0; i < 4; i++) {
            af[i]  = *(const bf16x8*)&As[(wm * 64 + i * 16 + l16) * LDA + quad * 8];
            bfr[i] = *(const bf16x8*)&Bs[(wn * 64 + i * 16 + l16) * LDA + quad * 8];
        }
        #pragma unroll
        for (int i = 0; i < 4; i++)
            #pragma unroll
            for (int j = 0; j < 4; j++)
                acc[i][j] = __builtin_amdgcn_mfma_f32_16x16x32_bf16(af[i], bfr[j], acc[i][j], 0, 0, 0);
        __syncthreads();
    }

    #pragma unroll
    for (int i = 0; i < 4; i++) {
        #pragma unroll
        for (int r = 0; r < 4; r++) {
            int row = bm + wm * 64 + i * 16 + quad * 4 + r;
            if (row < M) {
                #pragma unroll
                for (int j = 0; j < 4; j++) {
                    int col = bn + wn * 64 + j * 16 + l16;
                    size_t idx = (size_t)(col >> 5) * M * 32 + (size_t)row * 32 + (col & 31);
                    __builtin_nontemporal_store((short)f2bf(acc[i][j][r]), C + idx);
                }
            }
        }
    }
}

// ---------------- direct-slot CSR build + work-queue counter init ----------------
__global__ __launch_bounds__(256)
void init_cursor_kernel(int* __restrict__ cursor, int* __restrict__ wctr)
{
    int i = blockIdx.x * 256 + threadIdx.x;
    if (i < N_TOTAL) cursor[i] = i * SLOTS;
    if (i < 32) wctr[i] = 0;           // 3 layers x 8 per-chunk counters (+pad)
}

// Range-filtered edge scatter into fixed per-row slots: block b handles edge-chunk b>>3,
// row range (b&7)*7500..+7500. Writes for one span stay on one XCD -> L2 write combining.
__global__ __launch_bounds__(256)
void scatter_edges_kernel(const int* __restrict__ rows, const int* __restrict__ cols,
                          const float* __restrict__ vals, int* __restrict__ cursor,
                          unsigned* __restrict__ edges)
{
    const int b = blockIdx.x;
    const int g = b & 7;
    const int i = (b >> 3) * 256 + threadIdx.x;
    const int lo = g * (N_TOTAL / 8);
    const int hi = lo + (N_TOTAL / 8);
    int r = __builtin_nontemporal_load(&rows[i]);
    if (r >= lo && r < hi) {
        unsigned rec = (unsigned)cols[i] | ((unsigned)f2bf(vals[i]) << 16);
        int p = atomicAdd(&cursor[r], 1);
        edges[p] = rec;
    }
}

// ---------------- SpMM + bias + ReLU: HW-XCD-pinned chunks + persistent wave queues ----
// R6/R7/R8 plateaued at ~40% VALU with FETCH 235-298 MB: the chunk = bid&7 -> XCD
// affinity HEURISTIC drifted (R3's 66 MB FETCH proves the chunked layout can be
// L2-resident; R4+'s block shape broke the bid->XCD mapping). R9 makes affinity EXACT:
// each wave reads its physical XCD via s_getreg(HW_REG_XCC_ID) [measured: learn_hip m09]
// and processes ONLY chunk == XCD, pulling 16-row groups from a per-chunk atomic work
// queue until drained. By construction XCD c's L2 only ever sees slice c (3.84 MB
// < 4 MiB) -> gathers are ~200 cy L2 hits. 2048 persistent blocks >= machine capacity
// -> every XCD gets blocks -> every queue drains (correctness). Inner loop = R6 2-stage
// (edge granules prefetched 1 iteration ahead; per-group exec-masked bound; padded
// slots zeroed -> col 0, w 0). Wave = 16 groups x 4 lanes, 8 f32 acc/lane, no barriers.
// MODE 0: write packed bf16 h. MODE 1: fp32 scatter via pos.
template<int MODE>
__global__ __launch_bounds__(256)
void spmm_relu_kernel(const int* __restrict__ row_end, const unsigned* __restrict__ edges,
                      const u32x4* __restrict__ supportC, const float* __restrict__ bias,
                      u32x4* __restrict__ out_bf, float* __restrict__ out_f32,
                      const int* __restrict__ pos, int nrows, int ngroups,
                      int* __restrict__ wctr)
{
    int xcc;
    asm volatile("s_getreg_b32 %0, hwreg(HW_REG_XCC_ID)" : "=s"(xcc));
    const int chunk = xcc & 7;
    const int lane  = threadIdx.x & 63;
    const int gid   = lane >> 2;       // 16 row-groups per wave
    const int fl    = lane & 3;        // u32x4 index within 64-B chunk-row
    // chunk slice: [N_TOTAL][4] u32x4 (64 B per row)
    const u32x4* __restrict__ sb = supportC + (size_t)chunk * N_TOTAL * 4 + fl;
    const f32x4* bb = (const f32x4*)bias + chunk * 8 + fl * 2;
    const f32x4 bv0 = bb[0], bv1 = bb[1];

    for (;;) {
        int g;
        if (lane == 0) g = atomicAdd(&wctr[chunk], 1);
        g = __builtin_amdgcn_readfirstlane(g);
        if (g >= ngroups) break;

        const int r  = g * 16 + gid;
        const int rc = min(r, nrows - 1);
        const int start = rc * SLOTS;
        const int len   = row_end[rc] - start;      // 4-lane broadcast load
        const u32x4* __restrict__ ep = (const u32x4*)(edges + start);   // 16-B aligned

        float a[8] = {};
        u32x4 e0 = ep[0];              // slots 0..3 (zeroed pads if len small)
        u32x4 e1 = ep[1];              // slots 4..7
        for (int it = 0; it < len; it += 8) {       // per-group bound; exec-masked
            const int gq = it >> 2;
            u32x4 n0 = ep[gq + 2];     // prefetch next iteration's edge granules
            u32x4 n1 = ep[gq + 3];     // (over-read stays in row's zeroed slots)
            #pragma unroll
            for (int s = 0; s < 4; s++) {
                unsigned es = e0[s];   // padded slot: zeroed -> col 0, w 0
                u32x4 u = sb[(size_t)(es & 0xFFFFu) * 4];
                float w = bf_hi(es);
                #pragma unroll
                for (int k = 0; k < 4; k++) {
                    a[2*k]     += w * bf_lo(u[k]);
                    a[2*k + 1] += w * bf_hi(u[k]);
                }
            }
            #pragma unroll
            for (int s = 0; s < 4; s++) {
                unsigned es = e1[s];
                u32x4 u = sb[(size_t)(es & 0xFFFFu) * 4];
                float w = bf_hi(es);
                #pragma unroll
                for (int k = 0; k < 4; k++) {
                    a[2*k]     += w * bf_lo(u[k]);
                    a[2*k + 1] += w * bf_hi(u[k]);
                }
            }
            e0 = n0; e1 = n1;
        }

        float o[8];
        #pragma unroll
        for (int k = 0; k < 8; k++) {
            float bk = (k < 4) ? bv0[k] : bv1[k - 4];
            o[k] = fmaxf(a[k] + bk, 0.f);
        }
        if (r < nrows) {
            if (MODE == 1) {
                f32x4 q0 = {o[0], o[1], o[2], o[3]};
                f32x4 q1 = {o[4], o[5], o[6], o[7]};
                f32x4* dst = (f32x4*)out_f32 + (size_t)pos[r] * 64 + chunk * 8 + fl * 2;
                __builtin_nontemporal_store(q0, dst);
                __builtin_nontemporal_store(q1, dst + 1);
            } else {
                u32x4 q;
                #pragma unroll
                for (int k = 0; k < 4; k++)
                    q[k] = (unsigned)f2bf(o[2*k]) | ((unsigned)f2bf(o[2*k + 1]) << 16);
                __builtin_nontemporal_store(q, out_bf + (size_t)r * 32 + chunk * 4 + fl);
            }
        }
    }
}

extern "C" void kernel_launch(void* const* d_in, const int* in_sizes, int n_in,
                              void* d_out, int out_size, void* d_ws, size_t ws_size,
                              hipStream_t stream)
{
    const float* x     = (const float*)d_in[0];
    const float* motif = (const float*)d_in[1];
    const int*   rows  = (const int*)d_in[2];
    const int*   cols  = (const int*)d_in[3];
    const float* vals  = (const float*)d_in[4];
    const int*   pos   = (const int*)d_in[5];
    const float* w1 = (const float*)d_in[7];
    const float* b1 = (const float*)d_in[8];
    const float* w2 = (const float*)d_in[9];
    const float* b2 = (const float*)d_in[10];
    const float* w3 = (const float*)d_in[11];
    const float* b3 = (const float*)d_in[12];
    (void)ws_size; (void)n_in; (void)in_sizes;

    char* ws = (char*)d_ws;
    size_t off = 0;
    short* h_bf     = (short*)(ws + off); off += (size_t)N_TOTAL * NHID * 2;      // 30.72 MB
    short* support  = (short*)(ws + off); off += (size_t)N_TOTAL * NHID * 2;      // 30.72 MB (chunked)
    short* w1T      = (short*)(ws + off); off += (size_t)NHID * NFEAT * 2;
    short* w2T      = (short*)(ws + off); off += (size_t)NHID * NHID * 2;
    short* w3T      = (short*)(ws + off); off += (size_t)NHID * NHID * 2;
    int* cursor     = (int*)(ws + off);   off += 60032 * 4;
    int* wctr       = (int*)(ws + off);   off += 32 * 4;                          // 3x8 queue counters
    unsigned* edges = (unsigned*)(ws + off); off += (size_t)N_TOTAL * SLOTS * 4 + 256;  // 23.04 MB + pad

    // --- independent prep first ---
    hipMemsetAsync(d_out, 0, (size_t)out_size * sizeof(float), stream);
    hipMemsetAsync(edges, 0, (size_t)N_TOTAL * SLOTS * 4 + 256, stream);  // pads -> (col 0, w 0)
    cvt_w_all_kernel<<<NHID, 256, 0, stream>>>(w1, w2, w3, w1T, w2T, w3T);
    init_cursor_kernel<<<(N_TOTAL + 255) / 256, 256, 0, stream>>>(cursor, wctr);
    scatter_edges_kernel<<<(N_EDGE / 256) * 8, 256, 0, stream>>>(rows, cols, vals, cursor, edges);

    dim3 ggrid((N_TOTAL + 127) / 128, NHID / 128);
    const int PBLK = 2048;                      // persistent blocks >= machine capacity
    const int ngrp0 = N_TOTAL / 16;             // 3750 groups per chunk
    const int ngrp1 = N_X / 16;                 // 3125 groups per chunk

    // layer 1 (fp32 A converted during staging)
    gemm_bt_kernel<true><<<ggrid, 256, 0, stream>>>(x, motif, N_X, nullptr, w1T, support, N_TOTAL, NFEAT);
    spmm_relu_kernel<0><<<PBLK, 256, 0, stream>>>(cursor, edges, (const u32x4*)support, b1,
                                                  (u32x4*)h_bf, nullptr, nullptr, N_TOTAL, ngrp0, wctr);
    // layer 2
    gemm_bt_kernel<false><<<ggrid, 256, 0, stream>>>(nullptr, nullptr, 0, h_bf, w2T, support, N_TOTAL, NHID);
    spmm_relu_kernel<0><<<PBLK, 256, 0, stream>>>(cursor, edges, (const u32x4*)support, b2,
                                                  (u32x4*)h_bf, nullptr, nullptr, N_TOTAL, ngrp0, wctr + 8);
    // layer 3: only rows < N_X needed; fp32 scatter straight into d_out
    gemm_bt_kernel<false><<<ggrid, 256, 0, stream>>>(nullptr, nullptr, 0, h_bf, w3T, support, N_TOTAL, NHID);
    spmm_relu_kernel<1><<<PBLK, 256, 0, stream>>>(cursor, edges, (const u32x4*)support, b3,
                                                  nullptr, (float*)d_out, pos, N_X, ngrp1, wctr + 16);
}

// Round 10
// 755.827 us; speedup vs baseline: 2.2812x; 2.2812x over previous
//
#include <hip/hip_runtime.h>

#define N_TOTAL 60000
#define N_X     50000
#define N_EDGE  1920000
#define NFEAT   512
#define NHID    256
#define SLOTS   96      // fixed per-row edge capacity; Poisson(32) max over 60000 rows ~ 60
#define NCHUNK  8       // feature chunks of 32 feats (64 B bf16)

typedef __attribute__((ext_vector_type(8))) short bf16x8;
typedef __attribute__((ext_vector_type(4))) float f32x4;
typedef __attribute__((ext_vector_type(4))) unsigned u32x4;

__device__ __forceinline__ unsigned short f2bf(float f) {
    unsigned u = __float_as_uint(f);
    unsigned r = (u + 0x7FFFu + ((u >> 16) & 1u)) >> 16;   // RNE
    return (unsigned short)r;
}
__device__ __forceinline__ float bf_lo(unsigned u) { return __uint_as_float(u << 16); }
__device__ __forceinline__ float bf_hi(unsigned u) { return __uint_as_float(u & 0xFFFF0000u); }

// ---------------- all W[K][256] fp32 -> WT[256][K] bf16 in one kernel ----------------
__global__ __launch_bounds__(256)
void cvt_w_all_kernel(const float* __restrict__ w1, const float* __restrict__ w2,
                      const float* __restrict__ w3, short* __restrict__ w1T,
                      short* __restrict__ w2T, short* __restrict__ w3T)
{
    int n = blockIdx.x;
    for (int k = threadIdx.x; k < NFEAT; k += 256)
        w1T[(size_t)n * NFEAT + k] = (short)f2bf(w1[(size_t)k * NHID + n]);
    for (int k = threadIdx.x; k < NHID; k += 256)
        w2T[(size_t)n * NHID + k] = (short)f2bf(w2[(size_t)k * NHID + n]);
    for (int k = threadIdx.x; k < NHID; k += 256)
        w3T[(size_t)n * NHID + k] = (short)f2bf(w3[(size_t)k * NHID + n]);
}

// ---------------- GEMM v2: W-in-LDS, A-direct-to-register, near-barrier-free ----------
// C[M x 256] = A[M x K] @ BT[256 x K]^T, C in chunked layout C[(col>>5)][row][col&31].
// Old gemm_bt paid 2 barriers + full LDS round-trip of BOTH operands per 32-wide K-step
// (32 barriers/block at K=512). N=256 is tiny: a 128-col x 128-K W-panel fits in 41 KB
// LDS. v2 stages W once per 128-K half (2 barriers per half; 4-8 barriers/block total)
// into Ws[4 kblk][128 n][40] -- the [row][40] stride copies the proven bank-friendly
// geometry of the old kernel's Bs. A is never staged: each wave MFMA-loads its own A
// fragments straight from global (16 rows x 64 B contiguous segments per fragment set,
// L2/L3-served; for layer 1 the fp32->bf16 convert happens in-register).
// Block = 256 thr = 4 waves; wave w owns rows bm+w*32..+31; acc[2][8] f32x4/lane.
#define LDW 40

template<bool AF32>
__global__ __launch_bounds__(256)
void gemm_wlds_kernel(const float* __restrict__ Af, const float* __restrict__ A2f, int split,
                      const short* __restrict__ Ab, const short* __restrict__ BT,
                      short* __restrict__ C, int M, int K)
{
    __shared__ short Ws[4][128][LDW];
    const int t     = threadIdx.x;
    const int lane  = t & 63;
    const int wave  = t >> 6;
    const int l16   = lane & 15;
    const int quad  = lane >> 4;
    const int bm    = blockIdx.x * 128;
    const int bn    = blockIdx.y * 128;
    const int rowA0 = bm + wave * 32;          // this wave's 32 M-rows

    f32x4 acc[2][8] = {};

    const int wn = t >> 1;             // staging: 2 threads per W row
    const int q2 = (t & 1) * 2;        // each stages kblk pair {q2, q2+1}

    for (int kh = 0; kh < K; kh += 128) {
        __syncthreads();               // prior half's readers done before overwrite
        {
            const short* src = BT + (size_t)(bn + wn) * K + kh + q2 * 32;
            #pragma unroll
            for (int b = 0; b < 2; b++)
                #pragma unroll
                for (int v = 0; v < 4; v++)
                    *(bf16x8*)&Ws[q2 + b][wn][v * 8] = *(const bf16x8*)(src + b * 32 + v * 8);
        }
        __syncthreads();

        #pragma unroll
        for (int kb = 0; kb < 4; kb++) {
            const int kk = kh + kb * 32;
            bf16x8 af[2];
            #pragma unroll
            for (int i = 0; i < 2; i++) {
                const int row = rowA0 + i * 16 + l16;
                if (AF32) {
                    float4 v0 = {}, v1 = {};
                    if (row < M) {
                        const float* s = (row < split) ? Af + (size_t)row * K
                                                       : A2f + (size_t)(row - split) * K;
                        const float4* p = (const float4*)(s + kk + quad * 8);
                        v0 = p[0]; v1 = p[1];
                    }
                    short tmp[8] = {
                        (short)f2bf(v0.x), (short)f2bf(v0.y), (short)f2bf(v0.z), (short)f2bf(v0.w),
                        (short)f2bf(v1.x), (short)f2bf(v1.y), (short)f2bf(v1.z), (short)f2bf(v1.w)};
                    af[i] = *(const bf16x8*)tmp;
                } else {
                    bf16x8 a = {};
                    if (row < M) a = *(const bf16x8*)(Ab + (size_t)row * K + kk + quad * 8);
                    af[i] = a;
                }
            }
            #pragma unroll
            for (int j = 0; j < 8; j++) {
                bf16x8 bfr = *(const bf16x8*)&Ws[kb][j * 16 + l16][quad * 8];
                acc[0][j] = __builtin_amdgcn_mfma_f32_16x16x32_bf16(af[0], bfr, acc[0][j], 0, 0, 0);
                acc[1][j] = __builtin_amdgcn_mfma_f32_16x16x32_bf16(af[1], bfr, acc[1][j], 0, 0, 0);
            }
        }
    }

    #pragma unroll
    for (int i = 0; i < 2; i++) {
        #pragma unroll
        for (int r = 0; r < 4; r++) {
            int row = rowA0 + i * 16 + quad * 4 + r;
            if (row < M) {
                #pragma unroll
                for (int j = 0; j < 8; j++) {
                    int col = bn + j * 16 + l16;
                    size_t idx = (size_t)(col >> 5) * M * 32 + (size_t)row * 32 + (col & 31);
                    __builtin_nontemporal_store((short)f2bf(acc[i][j][r]), C + idx);
                }
            }
        }
    }
}

// ---------------- direct-slot CSR build ----------------
__global__ __launch_bounds__(256)
void init_cursor_kernel(int* __restrict__ cursor)
{
    int i = blockIdx.x * 256 + threadIdx.x;
    if (i < N_TOTAL) cursor[i] = i * SLOTS;
}

// Range-filtered edge scatter into fixed per-row slots: block b handles edge-chunk b>>3,
// row range (b&7)*7500..+7500. Writes for one span stay on one XCD -> L2 write combining.
__global__ __launch_bounds__(256)
void scatter_edges_kernel(const int* __restrict__ rows, const int* __restrict__ cols,
                          const float* __restrict__ vals, int* __restrict__ cursor,
                          unsigned* __restrict__ edges)
{
    const int b = blockIdx.x;
    const int g = b & 7;
    const int i = (b >> 3) * 256 + threadIdx.x;
    const int lo = g * (N_TOTAL / 8);
    const int hi = lo + (N_TOTAL / 8);
    int r = __builtin_nontemporal_load(&rows[i]);
    if (r >= lo && r < hi) {
        unsigned rec = (unsigned)cols[i] | ((unsigned)f2bf(vals[i]) << 16);
        int p = atomicAdd(&cursor[r], 1);
        edges[p] = rec;
    }
}

// ---------------- SpMM + bias + ReLU (exact R6 revert: best measured, 115 us) ---------
// Block = (row-group, chunk); chunk = bid & 7. Wave = 16 groups x 4 lanes; each group
// owns one (row, chunk), walks its edge list sequentially, accumulates 8 f32/lane in
// registers. Plain edge loads (nt poisons L3 for the 8x re-read — R5). 2-granule unroll
// with 1-iteration-ahead edge prefetch. Per-group exec-masked bound; padded slots
// zeroed (col 0, w 0); over-read granules stay inside the row's own zeroed slot block
// (max granule index 17 -> slot 71 < 96). No barriers anywhere.
// [R7/R8/R9 post-mortems: deeper pipelines and XCC-pinning all regress; this schedule
//  is the measured local optimum of the gather family.]
// MODE 0: write packed bf16 h. MODE 1: fp32 scatter via pos.
template<int MODE>
__global__ __launch_bounds__(256)
void spmm_relu_kernel(const int* __restrict__ row_end, const unsigned* __restrict__ edges,
                      const u32x4* __restrict__ supportC, const float* __restrict__ bias,
                      u32x4* __restrict__ out_bf, float* __restrict__ out_f32,
                      const int* __restrict__ pos, int nrows)
{
    const int chunk = blockIdx.x & 7;
    const int grp   = blockIdx.x >> 3;
    const int wave  = threadIdx.x >> 6;
    const int lane  = threadIdx.x & 63;
    const int gid   = lane >> 2;       // 16 row-groups per wave
    const int fl    = lane & 3;        // u32x4 index within 64-B chunk-row
    const int rbase = grp * 64 + wave * 16;
    if (rbase >= nrows) return;        // wave-uniform exit; kernel has no barriers
    const int r  = rbase + gid;
    const int rc = min(r, nrows - 1);
    const int start = rc * SLOTS;
    const int len   = row_end[rc] - start;          // 4-lane broadcast load
    const u32x4* __restrict__ sb = supportC + (size_t)chunk * N_TOTAL * 4 + fl;
    const u32x4* __restrict__ ep = (const u32x4*)(edges + start);   // 16-B aligned

    float a[8] = {};
    u32x4 e0 = ep[0];                  // slots 0..3 (zeroed pads if len small)
    u32x4 e1 = ep[1];                  // slots 4..7
    for (int it = 0; it < len; it += 8) {           // per-group bound; exec-masked
        const int g = it >> 2;
        u32x4 n0 = ep[g + 2];          // prefetch next iteration's granules
        u32x4 n1 = ep[g + 3];          // (over-read stays in row's zeroed slots)
        #pragma unroll
        for (int s = 0; s < 4; s++) {
            unsigned es = e0[s];       // padded slot: zeroed -> col 0, w 0
            u32x4 u = sb[(size_t)(es & 0xFFFFu) * 4];
            float w = bf_hi(es);
            #pragma unroll
            for (int k = 0; k < 4; k++) {
                a[2*k]     += w * bf_lo(u[k]);
                a[2*k + 1] += w * bf_hi(u[k]);
            }
        }
        #pragma unroll
        for (int s = 0; s < 4; s++) {
            unsigned es = e1[s];
            u32x4 u = sb[(size_t)(es & 0xFFFFu) * 4];
            float w = bf_hi(es);
            #pragma unroll
            for (int k = 0; k < 4; k++) {
                a[2*k]     += w * bf_lo(u[k]);
                a[2*k + 1] += w * bf_hi(u[k]);
            }
        }
        e0 = n0; e1 = n1;
    }

    const f32x4* bb = (const f32x4*)bias + chunk * 8 + fl * 2;
    f32x4 bv0 = bb[0], bv1 = bb[1];
    float o[8];
    #pragma unroll
    for (int k = 0; k < 8; k++) {
        float bk = (k < 4) ? bv0[k] : bv1[k - 4];
        o[k] = fmaxf(a[k] + bk, 0.f);
    }
    if (r < nrows) {
        if (MODE == 1) {
            f32x4 q0 = {o[0], o[1], o[2], o[3]};
            f32x4 q1 = {o[4], o[5], o[6], o[7]};
            f32x4* dst = (f32x4*)out_f32 + (size_t)pos[r] * 64 + chunk * 8 + fl * 2;
            __builtin_nontemporal_store(q0, dst);
            __builtin_nontemporal_store(q1, dst + 1);
        } else {
            u32x4 q;
            #pragma unroll
            for (int k = 0; k < 4; k++)
                q[k] = (unsigned)f2bf(o[2*k]) | ((unsigned)f2bf(o[2*k + 1]) << 16);
            __builtin_nontemporal_store(q, out_bf + (size_t)r * 32 + chunk * 4 + fl);
        }
    }
}

extern "C" void kernel_launch(void* const* d_in, const int* in_sizes, int n_in,
                              void* d_out, int out_size, void* d_ws, size_t ws_size,
                              hipStream_t stream)
{
    const float* x     = (const float*)d_in[0];
    const float* motif = (const float*)d_in[1];
    const int*   rows  = (const int*)d_in[2];
    const int*   cols  = (const int*)d_in[3];
    const float* vals  = (const float*)d_in[4];
    const int*   pos   = (const int*)d_in[5];
    const float* w1 = (const float*)d_in[7];
    const float* b1 = (const float*)d_in[8];
    const float* w2 = (const float*)d_in[9];
    const float* b2 = (const float*)d_in[10];
    const float* w3 = (const float*)d_in[11];
    const float* b3 = (const float*)d_in[12];
    (void)ws_size; (void)n_in; (void)in_sizes;

    char* ws = (char*)d_ws;
    size_t off = 0;
    short* h_bf     = (short*)(ws + off); off += (size_t)N_TOTAL * NHID * 2;      // 30.72 MB
    short* support  = (short*)(ws + off); off += (size_t)N_TOTAL * NHID * 2;      // 30.72 MB (chunked)
    short* w1T      = (short*)(ws + off); off += (size_t)NHID * NFEAT * 2;
    short* w2T      = (short*)(ws + off); off += (size_t)NHID * NHID * 2;
    short* w3T      = (short*)(ws + off); off += (size_t)NHID * NHID * 2;
    int* cursor     = (int*)(ws + off);   off += 60032 * 4;
    unsigned* edges = (unsigned*)(ws + off); off += (size_t)N_TOTAL * SLOTS * 4 + 256;  // 23.04 MB + pad

    // --- independent prep first ---
    hipMemsetAsync(d_out, 0, (size_t)out_size * sizeof(float), stream);
    hipMemsetAsync(edges, 0, (size_t)N_TOTAL * SLOTS * 4, stream);   // padded slots -> (col 0, w 0)
    cvt_w_all_kernel<<<NHID, 256, 0, stream>>>(w1, w2, w3, w1T, w2T, w3T);
    init_cursor_kernel<<<(N_TOTAL + 255) / 256, 256, 0, stream>>>(cursor);
    scatter_edges_kernel<<<(N_EDGE / 256) * 8, 256, 0, stream>>>(rows, cols, vals, cursor, edges);

    dim3 ggrid((N_TOTAL + 127) / 128, NHID / 128);
    const int sgrid0 = ((N_TOTAL + 63) / 64) * NCHUNK;
    const int sgrid1 = ((N_X + 63) / 64) * NCHUNK;

    // layer 1 (fp32 A converted in-register during fragment load)
    gemm_wlds_kernel<true><<<ggrid, 256, 0, stream>>>(x, motif, N_X, nullptr, w1T, support, N_TOTAL, NFEAT);
    spmm_relu_kernel<0><<<sgrid0, 256, 0, stream>>>(cursor, edges, (const u32x4*)support, b1,
                                                    (u32x4*)h_bf, nullptr, nullptr, N_TOTAL);
    // layer 2
    gemm_wlds_kernel<false><<<ggrid, 256, 0, stream>>>(nullptr, nullptr, 0, h_bf, w2T, support, N_TOTAL, NHID);
    spmm_relu_kernel<0><<<sgrid0, 256, 0, stream>>>(cursor, edges, (const u32x4*)support, b2,
                                                    (u32x4*)h_bf, nullptr, nullptr, N_TOTAL);
    // layer 3: only rows < N_X needed; fp32 scatter straight into d_out
    gemm_wlds_kernel<false><<<ggrid, 256, 0, stream>>>(nullptr, nullptr, 0, h_bf, w3T, support, N_TOTAL, NHID);
    spmm_relu_kernel<1><<<sgrid1, 256, 0, stream>>>(cursor, edges, (const u32x4*)support, b3,
                                                    nullptr, (float*)d_out, pos, N_X);
}

// Round 11
// 696.331 us; speedup vs baseline: 2.4762x; 1.0854x over previous
//
#include <hip/hip_runtime.h>

#define N_TOTAL 60000
#define N_X     50000
#define N_EDGE  1920000
#define NFEAT   512
#define NHID    256
#define SLOTS   96      // fixed per-row edge capacity; Poisson(32) max over 60000 rows ~ 60
#define NCHUNK  8       // feature chunks of 32 feats (64 B bf16)

typedef __attribute__((ext_vector_type(8))) short bf16x8;
typedef __attribute__((ext_vector_type(4))) float f32x4;
typedef __attribute__((ext_vector_type(4))) unsigned u32x4;

__device__ __forceinline__ unsigned short f2bf(float f) {
    unsigned u = __float_as_uint(f);
    unsigned r = (u + 0x7FFFu + ((u >> 16) & 1u)) >> 16;   // RNE
    return (unsigned short)r;
}
__device__ __forceinline__ float bf_lo(unsigned u) { return __uint_as_float(u << 16); }
__device__ __forceinline__ float bf_hi(unsigned u) { return __uint_as_float(u & 0xFFFF0000u); }

// ---------------- all W[K][256] fp32 -> WT[256][K] bf16 in one kernel ----------------
__global__ __launch_bounds__(256)
void cvt_w_all_kernel(const float* __restrict__ w1, const float* __restrict__ w2,
                      const float* __restrict__ w3, short* __restrict__ w1T,
                      short* __restrict__ w2T, short* __restrict__ w3T)
{
    int n = blockIdx.x;
    for (int k = threadIdx.x; k < NFEAT; k += 256)
        w1T[(size_t)n * NFEAT + k] = (short)f2bf(w1[(size_t)k * NHID + n]);
    for (int k = threadIdx.x; k < NHID; k += 256)
        w2T[(size_t)n * NHID + k] = (short)f2bf(w2[(size_t)k * NHID + n]);
    for (int k = threadIdx.x; k < NHID; k += 256)
        w3T[(size_t)n * NHID + k] = (short)f2bf(w3[(size_t)k * NHID + n]);
}

// ---------------- bf16 MFMA GEMM v3: 128 M x 256 N (full-N) tile, 8 waves -------------
// C[M x 256] = A[M x K] @ BT[256 x K]^T, C in chunked layout C[(col>>5)][row][col&31].
// Same proven inner geometry as gemm_bt (BK=32, LDA=40 bank layout [0 conflicts
// measured], 2-barrier K-step, LDS fragment reads, 16x16x32 MFMA) but ONE block now
// computes all 256 N-cols: the old (bm, bn) grid staged the same A-tile twice (R10
// post-mortem: GEMMs ~250-315 us; A-direct variant regressed, so staging stays, but
// the bn split's duplicate A traffic + thin 64-MFMA-per-barrier-pair go away).
// 512 thr = 8 waves = 2 M-halves x 4 N-quarters, each wave 64x64, acc[4][4] f32x4.
// Per K-step: 128 MFMA per block for 48 B/thread staging (old: 64 per 64 B/thread)
// -> staging+barrier cost per MFMA ~2.7x lower; A fetched once per M-row total.
// LDS = 30 KB -> ~4 blocks/CU.
#define LDA 40   // padded LDS row stride (shorts): 80B -> 2-way bank alias only (free)

template<bool AF32>
__global__ __launch_bounds__(512)
void gemm_bt_kernel(const float* __restrict__ Af, const float* __restrict__ A2f, int split,
                    const short* __restrict__ Ab, const short* __restrict__ BT,
                    short* __restrict__ C, int M, int K)
{
    __shared__ short As[128 * LDA];
    __shared__ short Bs[256 * LDA];
    const int t    = threadIdx.x;
    const int lane = t & 63;
    const int wave = t >> 6;
    const int wm   = wave & 1;         // M-half (64 rows)
    const int wn   = wave >> 1;        // N-quarter (64 cols)
    const int l16  = lane & 15;
    const int quad = lane >> 4;
    const int bm   = blockIdx.x * 128;

    f32x4 acc[4][4] = {};

    const int arow = t >> 2;           // A staging: 4 threads per row (0..127)
    const int asch = t & 3;
    const int brow = t >> 1;           // B staging: 2 threads per row (0..255)
    const int bh   = t & 1;

    for (int kk = 0; kk < K; kk += 32) {
        if (AF32) {
            int row = bm + arow;
            float4 v0 = {}, v1 = {};
            if (row < M) {
                const float* src = (row < split) ? (Af + (size_t)row * K)
                                                 : (A2f + (size_t)(row - split) * K);
                const float4* p = (const float4*)(src + kk + asch * 8);
                v0 = p[0]; v1 = p[1];
            }
            short tmp[8] = {
                (short)f2bf(v0.x), (short)f2bf(v0.y), (short)f2bf(v0.z), (short)f2bf(v0.w),
                (short)f2bf(v1.x), (short)f2bf(v1.y), (short)f2bf(v1.z), (short)f2bf(v1.w)};
            *(bf16x8*)&As[arow * LDA + asch * 8] = *(const bf16x8*)tmp;
        } else {
            bf16x8 va = {};
            int row = bm + arow;
            if (row < M) va = *(const bf16x8*)(Ab + (size_t)row * K + kk + asch * 8);
            *(bf16x8*)&As[arow * LDA + asch * 8] = va;
        }
        {
            const short* src = BT + (size_t)brow * K + kk + bh * 16;
            *(bf16x8*)&Bs[brow * LDA + bh * 16]     = *(const bf16x8*)(src);
            *(bf16x8*)&Bs[brow * LDA + bh * 16 + 8] = *(const bf16x8*)(src + 8);
        }
        __syncthreads();

        bf16x8 af[4], bfr[4];
        #pragma unroll
        for (int i = 0; i < 4; i++) {
            af[i]  = *(const bf16x8*)&As[(wm * 64 + i * 16 + l16) * LDA + quad * 8];
            bfr[i] = *(const bf16x8*)&Bs[(wn * 64 + i * 16 + l16) * LDA + quad * 8];
        }
        #pragma unroll
        for (int i = 0; i < 4; i++)
            #pragma unroll
            for (int j = 0; j < 4; j++)
                acc[i][j] = __builtin_amdgcn_mfma_f32_16x16x32_bf16(af[i], bfr[j], acc[i][j], 0, 0, 0);
        __syncthreads();
    }

    #pragma unroll
    for (int i = 0; i < 4; i++) {
        #pragma unroll
        for (int r = 0; r < 4; r++) {
            int row = bm + wm * 64 + i * 16 + quad * 4 + r;
            if (row < M) {
                #pragma unroll
                for (int j = 0; j < 4; j++) {
                    int col = wn * 64 + j * 16 + l16;
                    size_t idx = (size_t)(col >> 5) * M * 32 + (size_t)row * 32 + (col & 31);
                    __builtin_nontemporal_store((short)f2bf(acc[i][j][r]), C + idx);
                }
            }
        }
    }
}

// ---------------- direct-slot CSR build ----------------
__global__ __launch_bounds__(256)
void init_cursor_kernel(int* __restrict__ cursor)
{
    int i = blockIdx.x * 256 + threadIdx.x;
    if (i < N_TOTAL) cursor[i] = i * SLOTS;
}

// Range-filtered edge scatter into fixed per-row slots: block b handles edge-chunk b>>3,
// row range (b&7)*7500..+7500. Writes for one span stay on one XCD -> L2 write combining.
__global__ __launch_bounds__(256)
void scatter_edges_kernel(const int* __restrict__ rows, const int* __restrict__ cols,
                          const float* __restrict__ vals, int* __restrict__ cursor,
                          unsigned* __restrict__ edges)
{
    const int b = blockIdx.x;
    const int g = b & 7;
    const int i = (b >> 3) * 256 + threadIdx.x;
    const int lo = g * (N_TOTAL / 8);
    const int hi = lo + (N_TOTAL / 8);
    int r = __builtin_nontemporal_load(&rows[i]);
    if (r >= lo && r < hi) {
        unsigned rec = (unsigned)cols[i] | ((unsigned)f2bf(vals[i]) << 16);
        int p = atomicAdd(&cursor[r], 1);
        edges[p] = rec;
    }
}

// ---------------- SpMM + bias + ReLU (exact R6 schedule: best measured, 115 us) -------
// Block = (row-group, chunk); chunk = bid & 7. Wave = 16 groups x 4 lanes; each group
// owns one (row, chunk), walks its edge list sequentially, accumulates 8 f32/lane in
// registers. Plain edge loads (nt poisons L3 for the 8x re-read — R5). 2-granule unroll
// with 1-iteration-ahead edge prefetch. Per-group exec-masked bound; padded slots
// zeroed (col 0, w 0); over-read granules stay inside the row's own zeroed slot block.
// [R7/R8/R9: deeper pipelines and XCC-pinning all regress; this is the gather family's
//  measured local optimum.] MODE 0: packed bf16 h. MODE 1: fp32 scatter via pos.
template<int MODE>
__global__ __launch_bounds__(256)
void spmm_relu_kernel(const int* __restrict__ row_end, const unsigned* __restrict__ edges,
                      const u32x4* __restrict__ supportC, const float* __restrict__ bias,
                      u32x4* __restrict__ out_bf, float* __restrict__ out_f32,
                      const int* __restrict__ pos, int nrows)
{
    const int chunk = blockIdx.x & 7;
    const int grp   = blockIdx.x >> 3;
    const int wave  = threadIdx.x >> 6;
    const int lane  = threadIdx.x & 63;
    const int gid   = lane >> 2;       // 16 row-groups per wave
    const int fl    = lane & 3;        // u32x4 index within 64-B chunk-row
    const int rbase = grp * 64 + wave * 16;
    if (rbase >= nrows) return;        // wave-uniform exit; kernel has no barriers
    const int r  = rbase + gid;
    const int rc = min(r, nrows - 1);
    const int start = rc * SLOTS;
    const int len   = row_end[rc] - start;          // 4-lane broadcast load
    const u32x4* __restrict__ sb = supportC + (size_t)chunk * N_TOTAL * 4 + fl;
    const u32x4* __restrict__ ep = (const u32x4*)(edges + start);   // 16-B aligned

    float a[8] = {};
    u32x4 e0 = ep[0];                  // slots 0..3 (zeroed pads if len small)
    u32x4 e1 = ep[1];                  // slots 4..7
    for (int it = 0; it < len; it += 8) {           // per-group bound; exec-masked
        const int g = it >> 2;
        u32x4 n0 = ep[g + 2];          // prefetch next iteration's granules
        u32x4 n1 = ep[g + 3];          // (over-read stays in row's zeroed slots)
        #pragma unroll
        for (int s = 0; s < 4; s++) {
            unsigned es = e0[s];       // padded slot: zeroed -> col 0, w 0
            u32x4 u = sb[(size_t)(es & 0xFFFFu) * 4];
            float w = bf_hi(es);
            #pragma unroll
            for (int k = 0; k < 4; k++) {
                a[2*k]     += w * bf_lo(u[k]);
                a[2*k + 1] += w * bf_hi(u[k]);
            }
        }
        #pragma unroll
        for (int s = 0; s < 4; s++) {
            unsigned es = e1[s];
            u32x4 u = sb[(size_t)(es & 0xFFFFu) * 4];
            float w = bf_hi(es);
            #pragma unroll
            for (int k = 0; k < 4; k++) {
                a[2*k]     += w * bf_lo(u[k]);
                a[2*k + 1] += w * bf_hi(u[k]);
            }
        }
        e0 = n0; e1 = n1;
    }

    const f32x4* bb = (const f32x4*)bias + chunk * 8 + fl * 2;
    f32x4 bv0 = bb[0], bv1 = bb[1];
    float o[8];
    #pragma unroll
    for (int k = 0; k < 8; k++) {
        float bk = (k < 4) ? bv0[k] : bv1[k - 4];
        o[k] = fmaxf(a[k] + bk, 0.f);
    }
    if (r < nrows) {
        if (MODE == 1) {
            f32x4 q0 = {o[0], o[1], o[2], o[3]};
            f32x4 q1 = {o[4], o[5], o[6], o[7]};
            f32x4* dst = (f32x4*)out_f32 + (size_t)pos[r] * 64 + chunk * 8 + fl * 2;
            __builtin_nontemporal_store(q0, dst);
            __builtin_nontemporal_store(q1, dst + 1);
        } else {
            u32x4 q;
            #pragma unroll
            for (int k = 0; k < 4; k++)
                q[k] = (unsigned)f2bf(o[2*k]) | ((unsigned)f2bf(o[2*k + 1]) << 16);
            __builtin_nontemporal_store(q, out_bf + (size_t)r * 32 + chunk * 4 + fl);
        }
    }
}

extern "C" void kernel_launch(void* const* d_in, const int* in_sizes, int n_in,
                              void* d_out, int out_size, void* d_ws, size_t ws_size,
                              hipStream_t stream)
{
    const float* x     = (const float*)d_in[0];
    const float* motif = (const float*)d_in[1];
    const int*   rows  = (const int*)d_in[2];
    const int*   cols  = (const int*)d_in[3];
    const float* vals  = (const float*)d_in[4];
    const int*   pos   = (const int*)d_in[5];
    const float* w1 = (const float*)d_in[7];
    const float* b1 = (const float*)d_in[8];
    const float* w2 = (const float*)d_in[9];
    const float* b2 = (const float*)d_in[10];
    const float* w3 = (const float*)d_in[11];
    const float* b3 = (const float*)d_in[12];
    (void)ws_size; (void)n_in; (void)in_sizes;

    char* ws = (char*)d_ws;
    size_t off = 0;
    short* h_bf     = (short*)(ws + off); off += (size_t)N_TOTAL * NHID * 2;      // 30.72 MB
    short* support  = (short*)(ws + off); off += (size_t)N_TOTAL * NHID * 2;      // 30.72 MB (chunked)
    short* w1T      = (short*)(ws + off); off += (size_t)NHID * NFEAT * 2;
    short* w2T      = (short*)(ws + off); off += (size_t)NHID * NHID * 2;
    short* w3T      = (short*)(ws + off); off += (size_t)NHID * NHID * 2;
    int* cursor     = (int*)(ws + off);   off += 60032 * 4;
    unsigned* edges = (unsigned*)(ws + off); off += (size_t)N_TOTAL * SLOTS * 4 + 256;  // 23.04 MB + pad

    // --- independent prep first ---
    hipMemsetAsync(d_out, 0, (size_t)out_size * sizeof(float), stream);
    hipMemsetAsync(edges, 0, (size_t)N_TOTAL * SLOTS * 4, stream);   // padded slots -> (col 0, w 0)
    cvt_w_all_kernel<<<NHID, 256, 0, stream>>>(w1, w2, w3, w1T, w2T, w3T);
    init_cursor_kernel<<<(N_TOTAL + 255) / 256, 256, 0, stream>>>(cursor);
    scatter_edges_kernel<<<(N_EDGE / 256) * 8, 256, 0, stream>>>(rows, cols, vals, cursor, edges);

    const int ggrid = (N_TOTAL + 127) / 128;    // 469 blocks, full-N tile
    const int sgrid0 = ((N_TOTAL + 63) / 64) * NCHUNK;
    const int sgrid1 = ((N_X + 63) / 64) * NCHUNK;

    // layer 1 (fp32 A converted during staging)
    gemm_bt_kernel<true><<<ggrid, 512, 0, stream>>>(x, motif, N_X, nullptr, w1T, support, N_TOTAL, NFEAT);
    spmm_relu_kernel<0><<<sgrid0, 256, 0, stream>>>(cursor, edges, (const u32x4*)support, b1,
                                                    (u32x4*)h_bf, nullptr, nullptr, N_TOTAL);
    // layer 2
    gemm_bt_kernel<false><<<ggrid, 512, 0, stream>>>(nullptr, nullptr, 0, h_bf, w2T, support, N_TOTAL, NHID);
    spmm_relu_kernel<0><<<sgrid0, 256, 0, stream>>>(cursor, edges, (const u32x4*)support, b2,
                                                    (u32x4*)h_bf, nullptr, nullptr, N_TOTAL);
    // layer 3: only rows < N_X needed; fp32 scatter straight into d_out
    gemm_bt_kernel<false><<<ggrid, 512, 0, stream>>>(nullptr, nullptr, 0, h_bf, w3T, support, N_TOTAL, NHID);
    spmm_relu_kernel<1><<<sgrid1, 256, 0, stream>>>(cursor, edges, (const u32x4*)support, b3,
                                                    nullptr, (float*)d_out, pos, N_X);
}